// Round 1
// baseline (106.677 us; speedup 1.0000x reference)
//
#include <hip/hip_runtime.h>
#include <math.h>

#define L_C 1024
#define B_C 32
#define F_C 24
#define S_C 12
#define N_C (L_C*B_C)   // 32768
#define DWIN 20
#define NB 4            // n's per block in fuse kernel

// ---------------------------------------------------------------------------
// Kernel A: windowed Gaussian message passing.
//   mp[t] = (1/max(t,1))     * sum_{d=1..min(t,DWIN)}     K(d) * x[t-d]
//   mf[t] = (1/max(L-1-t,1)) * sum_{d=1..min(L-1-t,DWIN)} K(d) * x[t+d]
// K(d) = exp(-d^2/8); tail beyond d=20 is < 1e-21 -> identical to dense ref.
// One thread per (t,b,c) element; neighbors in wave are consecutive -> coalesced.
// ---------------------------------------------------------------------------
__global__ void msg_kernel(const float* __restrict__ x, float* __restrict__ mp,
                           float* __restrict__ mf, int C) {
    int idx = blockIdx.x * 256 + threadIdx.x;
    int stride = B_C * C;
    int total = N_C * C;
    if (idx >= total) return;
    int t = idx / stride;
    float accp = 0.f, accf = 0.f;
    #pragma unroll
    for (int d = 1; d <= DWIN; ++d) {
        float w = expf(-0.125f * (float)(d * d));
        if (t >= d)        accp += w * x[idx - d * stride];
        if (t + d < L_C)   accf += w * x[idx + d * stride];
    }
    mp[idx] = accp / fmaxf((float)t, 1.0f);
    mf[idx] = accf / fmaxf((float)(L_C - 1 - t), 1.0f);
}

// 32-wide segment reductions (lanes 0-31 and 32-63 reduce independently)
__device__ inline float segred_max(float v) {
    #pragma unroll
    for (int o = 16; o >= 1; o >>= 1) v = fmaxf(v, __shfl_xor(v, o, 32));
    return v;
}
__device__ inline float segred_sum(float v) {
    #pragma unroll
    for (int o = 16; o >= 1; o >>= 1) v += __shfl_xor(v, o, 32);
    return v;
}

// ---------------------------------------------------------------------------
// Kernel B: fused per-n update + softmax + loss partials.
// 1 wave = 1 n. Lanes 0..23 own next_f[g], lanes 32..43 own next_s[t].
// Matrices staged in LDS with padded strides 25 / 13 (coprime with 32 banks).
// ---------------------------------------------------------------------------
__global__ __launch_bounds__(256) void fuse_kernel(
    const float* __restrict__ f,  const float* __restrict__ s,
    const float* __restrict__ fs, const float* __restrict__ ff,
    const float* __restrict__ ss, const float* __restrict__ fst,
    const float* __restrict__ sft,
    const int* __restrict__ fl, const int* __restrict__ sl,
    const int* __restrict__ yl, const int* __restrict__ y2f,
    const int* __restrict__ y2s,
    const float* __restrict__ fmp, const float* __restrict__ fmf,
    const float* __restrict__ smp, const float* __restrict__ smf,
    float* __restrict__ outf, float* __restrict__ outs,
    float* __restrict__ part)
{
    __shared__ float FFs[NB*600];   // 24 rows, stride 25
    __shared__ float FSs[NB*312];   // 24 rows, stride 13
    __shared__ float SSs[NB*156];   // 12 rows, stride 13
    __shared__ float FSTs[NB*312];  // 24 rows, stride 13
    __shared__ float SFTs[NB*300];  // 12 rows, stride 25
    __shared__ float VF[NB*24], VS[NB*12];
    __shared__ float VFMP[NB*24], VFMF[NB*24], VSMP[NB*12], VSMF[NB*12];
    __shared__ float lossbuf[NB];

    const int tid = threadIdx.x;
    const int n0 = blockIdx.x * NB;

    // ---- stage matrices (coalesced float4 global loads, padded LDS writes) ----
    {   // ff: NB*576 floats = NB*144 float4
        const float4* g = (const float4*)(ff + (size_t)n0 * 576);
        for (int i = tid; i < NB*144; i += 256) {
            float4 v = g[i];
            int flat = i*4, n = flat/576, rem = flat - n*576;
            int r = rem/24, c = rem - r*24;
            float* d = &FFs[n*600 + r*25 + c];
            d[0]=v.x; d[1]=v.y; d[2]=v.z; d[3]=v.w;
        }
    }
    {   // fs: NB*288 floats
        const float4* g = (const float4*)(fs + (size_t)n0 * 288);
        for (int i = tid; i < NB*72; i += 256) {
            float4 v = g[i];
            int flat = i*4, n = flat/288, rem = flat - n*288;
            int r = rem/12, c = rem - r*12;
            float* d = &FSs[n*312 + r*13 + c];
            d[0]=v.x; d[1]=v.y; d[2]=v.z; d[3]=v.w;
        }
    }
    {   // fs_t: NB*288 floats
        const float4* g = (const float4*)(fst + (size_t)n0 * 288);
        for (int i = tid; i < NB*72; i += 256) {
            float4 v = g[i];
            int flat = i*4, n = flat/288, rem = flat - n*288;
            int r = rem/12, c = rem - r*12;
            float* d = &FSTs[n*312 + r*13 + c];
            d[0]=v.x; d[1]=v.y; d[2]=v.z; d[3]=v.w;
        }
    }
    {   // ss: NB*144 floats
        const float4* g = (const float4*)(ss + (size_t)n0 * 144);
        for (int i = tid; i < NB*36; i += 256) {
            float4 v = g[i];
            int flat = i*4, n = flat/144, rem = flat - n*144;
            int r = rem/12, c = rem - r*12;
            float* d = &SSs[n*156 + r*13 + c];
            d[0]=v.x; d[1]=v.y; d[2]=v.z; d[3]=v.w;
        }
    }
    {   // sf_t: NB*288 floats, 12 rows x 24 cols
        const float4* g = (const float4*)(sft + (size_t)n0 * 288);
        for (int i = tid; i < NB*72; i += 256) {
            float4 v = g[i];
            int flat = i*4, n = flat/288, rem = flat - n*288;
            int r = rem/24, c = rem - r*24;
            float* d = &SFTs[n*300 + r*25 + c];
            d[0]=v.x; d[1]=v.y; d[2]=v.z; d[3]=v.w;
        }
    }
    // vectors
    for (int i = tid; i < NB*24; i += 256) {
        int gi = n0*24 + i;
        VF[i] = f[gi]; VFMP[i] = fmp[gi]; VFMF[i] = fmf[gi];
    }
    for (int i = tid; i < NB*12; i += 256) {
        int gi = n0*12 + i;
        VS[i] = s[gi]; VSMP[i] = smp[gi]; VSMF[i] = smf[gi];
    }
    __syncthreads();

    const int w    = tid >> 6;
    const int lane = tid & 63;
    const int n    = n0 + w;

    const float* vf   = &VF[w*24];
    const float* vs   = &VS[w*12];
    const float* vfmp = &VFMP[w*24];
    const float* vfmf = &VFMF[w*24];
    const float* vsmp = &VSMP[w*12];
    const float* vsmf = &VSMF[w*12];
    const float* mFF  = &FFs[w*600];
    const float* mFS  = &FSs[w*312];
    const float* mSS  = &SSs[w*156];
    const float* mFST = &FSTs[w*312];
    const float* mSFT = &SFTs[w*300];

    float nf = -INFINITY, ns = -INFINITY;
    if (lane < 24) {
        const int g = lane;
        float acc = 0.f;
        #pragma unroll
        for (int k = 0; k < 24; ++k) acc += vfmp[k] * mFF[k*25 + g];   // f_mp . ff[:,g]
        #pragma unroll
        for (int k = 0; k < 24; ++k) acc += mFF[g*25 + k] * vfmf[k];   // ff[g,:] . f_mf
        #pragma unroll
        for (int k = 0; k < 12; ++k) acc += vsmp[k] * mSFT[k*25 + g];  // s_mp . sf_t[:,g]
        #pragma unroll
        for (int k = 0; k < 12; ++k) acc += mFST[g*13 + k] * vsmf[k];  // fs_t[g,:] . s_mf
        #pragma unroll
        for (int k = 0; k < 12; ++k) acc += mFS[g*13 + k] * vs[k];     // fs[g,:] . orig_s
        nf = vf[g] + 0.5f * acc;
    } else if (lane >= 32 && lane < 44) {
        const int t = lane - 32;
        float acc = 0.f;
        #pragma unroll
        for (int k = 0; k < 12; ++k) acc += vsmp[k] * mSS[k*13 + t];   // s_mp . ss[:,t]
        #pragma unroll
        for (int k = 0; k < 12; ++k) acc += mSS[t*13 + k] * vsmf[k];   // ss[t,:] . s_mf
        #pragma unroll
        for (int k = 0; k < 24; ++k) acc += vfmp[k] * mFST[k*13 + t];  // f_mp . fs_t[:,t]
        #pragma unroll
        for (int k = 0; k < 24; ++k) acc += mSFT[t*25 + k] * vfmf[k];  // sf_t[t,:] . f_mf
        #pragma unroll
        for (int k = 0; k < 24; ++k) acc += vf[k] * mFS[k*13 + t];     // orig_f . fs[:,t]
        ns = vs[t] + 0.5f * acc;
    }

    // ---- softmax/LSE of ORIGINAL logits (for CE1, CE2, struct) ----
    float xo;
    if (lane < 32) xo = (lane < 24) ? vf[lane] : -INFINITY;
    else           xo = (lane < 44) ? vs[lane - 32] : -INFINITY;
    float mo = segred_max(xo);
    float eo = expf(xo - mo);           // expf(-inf) = 0 for invalid lanes
    float so = segred_sum(eo);
    float lse_o = mo + logf(so);

    // ---- softmax/LSE of NEXT logits (output probs + CE3, CE4) ----
    float xn = (lane < 32) ? nf : ns;   // invalid lanes hold -inf
    float mn = segred_max(xn);
    float en = expf(xn - mn);
    float sn = segred_sum(en);
    float p  = en / sn;
    float lse_n = mn + logf(sn);

    if (lane < 24)               outf[(size_t)n*24 + lane]        = p;
    if (lane >= 32 && lane < 44) outs[(size_t)n*12 + (lane - 32)] = p;

    // ---- loss pieces (mask is identically 1) ----
    int fln = fl[n], sln = sl[n], yln = yl[n];
    float lse_o_up = __shfl(lse_o, 32, 64);
    float lse_n_up = __shfl(lse_n, 32, 64);
    float nf_at    = __shfl(nf, fln, 64);
    float ns_at    = __shfl(ns, 32 + sln, 64);
    if (lane == 0) {
        float ce1 = lse_o - vf[fln];                      // CE(orig_f)
        float ce2 = lse_o_up - vs[sln];                   // CE(orig_s)
        float st  = -expf(vf[y2f[yln]] - lse_o)
                  *  expf(vs[y2s[yln]] - lse_o_up);       // -p_f[yf]*p_s[ys]
        float ce3 = lse_n - nf_at;                        // CE(next_f)
        float ce4 = lse_n_up - ns_at;                     // CE(next_s)
        lossbuf[w] = ce1 + ce2 + st + ce3 + ce4;
    }
    __syncthreads();
    if (tid == 0)
        part[blockIdx.x] = lossbuf[0] + lossbuf[1] + lossbuf[2] + lossbuf[3];
}

// ---------------------------------------------------------------------------
// Kernel C: deterministic fixed-order loss reduction (no float atomics).
// ---------------------------------------------------------------------------
__global__ void loss_reduce(const float* __restrict__ part, float* __restrict__ out) {
    __shared__ float sm[256];
    float a = 0.f;
    for (int i = threadIdx.x; i < N_C/NB; i += 256) a += part[i];
    sm[threadIdx.x] = a;
    __syncthreads();
    for (int o = 128; o >= 1; o >>= 1) {
        if ((int)threadIdx.x < o) sm[threadIdx.x] += sm[threadIdx.x + o];
        __syncthreads();
    }
    if (threadIdx.x == 0) out[0] = sm[0] * (1.0f / (float)N_C);
}

extern "C" void kernel_launch(void* const* d_in, const int* in_sizes, int n_in,
                              void* d_out, int out_size, void* d_ws, size_t ws_size,
                              hipStream_t stream) {
    (void)in_sizes; (void)n_in; (void)out_size; (void)ws_size;

    const float* f   = (const float*)d_in[0];
    const float* s   = (const float*)d_in[1];
    const float* fs  = (const float*)d_in[2];
    const float* ff  = (const float*)d_in[3];
    const float* ss  = (const float*)d_in[4];
    const float* fst = (const float*)d_in[5];
    const float* sft = (const float*)d_in[6];
    const int* fl  = (const int*)d_in[7];
    const int* sl  = (const int*)d_in[8];
    const int* yl  = (const int*)d_in[9];
    // d_in[10] = mask, identically true -> unused
    const int* y2f = (const int*)d_in[11];
    const int* y2s = (const int*)d_in[12];

    float* ws   = (float*)d_ws;
    float* fmp  = ws;
    float* fmf  = fmp + (size_t)N_C * F_C;
    float* smp  = fmf + (size_t)N_C * F_C;
    float* smf  = smp + (size_t)N_C * S_C;
    float* part = smf + (size_t)N_C * S_C;   // N_C/NB = 8192 partials

    float* outf = (float*)d_out;
    float* outs = outf + (size_t)N_C * F_C;
    float* outl = outs + (size_t)N_C * S_C;

    msg_kernel<<<(N_C * F_C) / 256, 256, 0, stream>>>(f, fmp, fmf, F_C);
    msg_kernel<<<(N_C * S_C) / 256, 256, 0, stream>>>(s, smp, smf, S_C);
    fuse_kernel<<<N_C / NB, 256, 0, stream>>>(f, s, fs, ff, ss, fst, sft,
                                              fl, sl, yl, y2f, y2s,
                                              fmp, fmf, smp, smf,
                                              outf, outs, part);
    loss_reduce<<<1, 256, 0, stream>>>(part, outl);
}

// Round 2
// 99.760 us; speedup vs baseline: 1.0693x; 1.0693x over previous
//
#include <hip/hip_runtime.h>
#include <math.h>

#define L_C 1024
#define B_C 32
#define F_C 24
#define S_C 12
#define N_C (L_C*B_C)   // 32768
#define DWIN 20
#define NB 4            // n's per block (1 wave per n)

// ---------------------------------------------------------------------------
// Kernel A: windowed Gaussian message passing (tail beyond d=20 < 1e-21).
// ---------------------------------------------------------------------------
__global__ void msg_kernel(const float* __restrict__ x, float* __restrict__ mp,
                           float* __restrict__ mf, int C) {
    int idx = blockIdx.x * 256 + threadIdx.x;
    int stride = B_C * C;
    int total = N_C * C;
    if (idx >= total) return;
    int t = idx / stride;
    float accp = 0.f, accf = 0.f;
    #pragma unroll
    for (int d = 1; d <= DWIN; ++d) {
        float w = expf(-0.125f * (float)(d * d));
        if (t >= d)        accp += w * x[idx - d * stride];
        if (t + d < L_C)   accf += w * x[idx + d * stride];
    }
    mp[idx] = accp / fmaxf((float)t, 1.0f);
    mf[idx] = accf / fmaxf((float)(L_C - 1 - t), 1.0f);
}

__device__ inline float segred_max(float v) {
    #pragma unroll
    for (int o = 16; o >= 1; o >>= 1) v = fmaxf(v, __shfl_xor(v, o, 32));
    return v;
}
__device__ inline float segred_sum(float v) {
    #pragma unroll
    for (int o = 16; o >= 1; o >>= 1) v += __shfl_xor(v, o, 32);
    return v;
}

// ---------------------------------------------------------------------------
// Kernel B v2: fused per-n update + softmax + loss partials.
// 1 wave = 1 n (wave-uniform n -> vectors live in SGPRs via scalar loads).
// Lanes 0..23 own next_f[g]; lanes 32..43 own next_s[t].
// LDS holds ONLY the five matrices:
//   FF  24 rows stride 28 (pad 4 -> 16B-aligned rows, <=3-way conflicts)
//   SFT 12 rows stride 28
//   FS / FST 24x12 stride 12 (linear copy), SS 12x12 stride 12
// Dot products paired by shared vector so f- and s-lanes run the SAME loop:
//   P1: vfmp . {ff[:,g] | fst[:,t]}      (b32 col reads, conflict-free)
//   P2: {ff[g,:] | sft[t,:]} . vfmf      (b128 row reads)
//   P3: vsmp . {sft[:,g] | ss[:,t]}      (b32 col reads)
//   P4: {fst[g,:] | ss[t,:]} . vsmf      (b128 row reads)
//   P5: f: fs[g,:].s (b128) | s: f.fs[:,t] (b32)   (divergent; different vecs)
// ---------------------------------------------------------------------------
__global__ __launch_bounds__(256) void fuse_kernel(
    const float* __restrict__ f,  const float* __restrict__ s,
    const float* __restrict__ fs, const float* __restrict__ ff,
    const float* __restrict__ ss, const float* __restrict__ fst,
    const float* __restrict__ sft,
    const int* __restrict__ fl, const int* __restrict__ sl,
    const int* __restrict__ yl, const int* __restrict__ y2f,
    const int* __restrict__ y2s,
    const float* __restrict__ fmp, const float* __restrict__ fmf,
    const float* __restrict__ smp, const float* __restrict__ smf,
    float* __restrict__ outf, float* __restrict__ outs,
    float* __restrict__ part)
{
    __shared__ float FFs [NB*672];   // 24 rows, stride 28
    __shared__ float SFTs[NB*336];   // 12 rows, stride 28
    __shared__ float FSs [NB*288];   // 24x12, linear
    __shared__ float FSTs[NB*288];   // 24x12, linear
    __shared__ float SSs [NB*144];   // 12x12, linear
    __shared__ float lossbuf[NB];

    const int tid = threadIdx.x;
    const int n0 = blockIdx.x * NB;

    // ---- stage matrices ----
    {   // ff: pad rows to stride 28
        const float4* g4 = (const float4*)(ff + (size_t)n0 * 576);
        for (int i = tid; i < NB*144; i += 256) {
            float4 v = g4[i];
            int flat = i*4, n = flat/576, rem = flat - n*576;
            int r = rem/24, c = rem - r*24;
            *(float4*)&FFs[n*672 + r*28 + c] = v;
        }
    }
    {   // sft: 12x24, pad rows to stride 28
        const float4* g4 = (const float4*)(sft + (size_t)n0 * 288);
        for (int i = tid; i < NB*72; i += 256) {
            float4 v = g4[i];
            int flat = i*4, n = flat/288, rem = flat - n*288;
            int r = rem/24, c = rem - r*24;
            *(float4*)&SFTs[n*336 + r*28 + c] = v;
        }
    }
    {   // fs, fst, ss: linear copies
        const float4* g4 = (const float4*)(fs + (size_t)n0 * 288);
        for (int i = tid; i < NB*72; i += 256) *(float4*)&FSs[i*4] = g4[i];
    }
    {
        const float4* g4 = (const float4*)(fst + (size_t)n0 * 288);
        for (int i = tid; i < NB*72; i += 256) *(float4*)&FSTs[i*4] = g4[i];
    }
    {
        const float4* g4 = (const float4*)(ss + (size_t)n0 * 144);
        for (int i = tid; i < NB*36; i += 256) *(float4*)&SSs[i*4] = g4[i];
    }
    __syncthreads();

    const int w    = tid >> 6;
    const int lane = tid & 63;
    const int n    = n0 + w;
    const int nu   = __builtin_amdgcn_readfirstlane(n);   // wave-uniform

    const bool isF   = lane < 32;
    const bool active = (lane < 24) | (lane >= 32 && lane < 44);
    const int g = (lane < 24) ? lane : 23;          // f output index (clamped)
    const int t = ((lane & 31) < 12) ? (lane & 31) : 11;  // s output index

    const float* sFF  = &FFs [w*672];
    const float* sSFT = &SFTs[w*336];
    const float* sFS  = &FSs [w*288];
    const float* sFST = &FSTs[w*288];
    const float* sSS  = &SSs [w*144];

    // wave-uniform vector pointers -> scalar loads
    const float* vmpf = fmp + (size_t)nu*24;
    const float* vmff = fmf + (size_t)nu*24;
    const float* vmps = smp + (size_t)nu*12;
    const float* vmfs = smf + (size_t)nu*12;
    const float* vF   = f   + (size_t)nu*24;
    const float* vS   = s   + (size_t)nu*12;

    float acc = 0.f;
    // P1: vfmp . {ff col g | fst col t}
    {
        const float* p = isF ? (sFF + g) : (sFST + t);
        const int st   = isF ? 28 : 12;
        #pragma unroll
        for (int k = 0; k < 24; ++k) acc += vmpf[k] * p[k*st];
    }
    // P2: {ff row g | sft row t} . vfmf   (b128)
    {
        const float4* q  = (const float4*)(isF ? (sFF + g*28) : (sSFT + t*28));
        const float4* v4 = (const float4*)vmff;
        #pragma unroll
        for (int k = 0; k < 6; ++k) {
            float4 a = q[k], b = v4[k];
            acc += a.x*b.x + a.y*b.y + a.z*b.z + a.w*b.w;
        }
    }
    // P3: vsmp . {sft col g | ss col t}
    {
        const float* p = isF ? (sSFT + g) : (sSS + t);
        const int st   = isF ? 28 : 12;
        #pragma unroll
        for (int k = 0; k < 12; ++k) acc += vmps[k] * p[k*st];
    }
    // P4: {fst row g | ss row t} . vsmf   (b128)
    {
        const float4* q  = (const float4*)(isF ? (sFST + g*12) : (sSS + t*12));
        const float4* v4 = (const float4*)vmfs;
        #pragma unroll
        for (int k = 0; k < 3; ++k) {
            float4 a = q[k], b = v4[k];
            acc += a.x*b.x + a.y*b.y + a.z*b.z + a.w*b.w;
        }
    }
    // P5: divergent (different vectors per role)
    if (isF) {
        const float4* q  = (const float4*)(sFS + g*12);
        const float4* v4 = (const float4*)vS;
        #pragma unroll
        for (int k = 0; k < 3; ++k) {
            float4 a = q[k], b = v4[k];
            acc += a.x*b.x + a.y*b.y + a.z*b.z + a.w*b.w;
        }
    } else {
        const float* p = sFS + t;
        #pragma unroll
        for (int k = 0; k < 24; ++k) acc += vF[k] * p[k*12];
    }

    // per-lane original logit (coalesced vector load)
    float fval = 0.f;
    if (lane < 24)                fval = vF[lane];
    else if (lane >= 32 && lane < 44) fval = vS[lane - 32];

    float nx = fval + 0.5f * acc;           // next logit for active lanes

    float xo = active ? fval : -INFINITY;
    float xn = active ? nx   : -INFINITY;

    // softmax/LSE of original logits
    float mo = segred_max(xo);
    float eo = expf(xo - mo);
    float so = segred_sum(eo);
    float lse_o = mo + logf(so);

    // softmax/LSE of next logits
    float mn = segred_max(xn);
    float en = expf(xn - mn);
    float sn = segred_sum(en);
    float p  = en / sn;
    float lse_n = mn + logf(sn);

    if (lane < 24)                outf[(size_t)n*24 + lane]        = p;
    else if (lane >= 32 && lane < 44) outs[(size_t)n*12 + (lane - 32)] = p;

    // ---- loss pieces (mask identically 1); labels via scalar loads ----
    const int fln = fl[nu], sln = sl[nu], yln = yl[nu];
    const int yfi = y2f[yln], ysi = y2s[yln];
    float lse_o_s = __shfl(lse_o, 32, 64);
    float lse_n_s = __shfl(lse_n, 32, 64);
    float vf_fl   = __shfl(xo, fln, 64);
    float vs_sl   = __shfl(xo, 32 + sln, 64);
    float nf_fl   = __shfl(xn, fln, 64);
    float ns_sl   = __shfl(xn, 32 + sln, 64);
    float vf_y    = __shfl(xo, yfi, 64);
    float vs_y    = __shfl(xo, 32 + ysi, 64);
    if (lane == 0) {
        float ce1 = lse_o   - vf_fl;
        float ce2 = lse_o_s - vs_sl;
        float st  = -expf(vf_y - lse_o) * expf(vs_y - lse_o_s);
        float ce3 = lse_n   - nf_fl;
        float ce4 = lse_n_s - ns_sl;
        lossbuf[w] = ce1 + ce2 + st + ce3 + ce4;
    }
    __syncthreads();
    if (tid == 0)
        part[blockIdx.x] = lossbuf[0] + lossbuf[1] + lossbuf[2] + lossbuf[3];
}

// ---------------------------------------------------------------------------
// Kernel C: deterministic fixed-order loss reduction.
// ---------------------------------------------------------------------------
__global__ void loss_reduce(const float* __restrict__ part, float* __restrict__ out) {
    __shared__ float sm[256];
    float a = 0.f;
    for (int i = threadIdx.x; i < N_C/NB; i += 256) a += part[i];
    sm[threadIdx.x] = a;
    __syncthreads();
    for (int o = 128; o >= 1; o >>= 1) {
        if ((int)threadIdx.x < o) sm[threadIdx.x] += sm[threadIdx.x + o];
        __syncthreads();
    }
    if (threadIdx.x == 0) out[0] = sm[0] * (1.0f / (float)N_C);
}

extern "C" void kernel_launch(void* const* d_in, const int* in_sizes, int n_in,
                              void* d_out, int out_size, void* d_ws, size_t ws_size,
                              hipStream_t stream) {
    (void)in_sizes; (void)n_in; (void)out_size; (void)ws_size;

    const float* f   = (const float*)d_in[0];
    const float* s   = (const float*)d_in[1];
    const float* fs  = (const float*)d_in[2];
    const float* ff  = (const float*)d_in[3];
    const float* ss  = (const float*)d_in[4];
    const float* fst = (const float*)d_in[5];
    const float* sft = (const float*)d_in[6];
    const int* fl  = (const int*)d_in[7];
    const int* sl  = (const int*)d_in[8];
    const int* yl  = (const int*)d_in[9];
    const int* y2f = (const int*)d_in[11];
    const int* y2s = (const int*)d_in[12];

    float* ws   = (float*)d_ws;
    float* fmp  = ws;
    float* fmf  = fmp + (size_t)N_C * F_C;
    float* smp  = fmf + (size_t)N_C * F_C;
    float* smf  = smp + (size_t)N_C * S_C;
    float* part = smf + (size_t)N_C * S_C;   // N_C/NB partials

    float* outf = (float*)d_out;
    float* outs = outf + (size_t)N_C * F_C;
    float* outl = outs + (size_t)N_C * S_C;

    msg_kernel<<<(N_C * F_C) / 256, 256, 0, stream>>>(f, fmp, fmf, F_C);
    msg_kernel<<<(N_C * S_C) / 256, 256, 0, stream>>>(s, smp, smf, S_C);
    fuse_kernel<<<N_C / NB, 256, 0, stream>>>(f, s, fs, ff, ss, fst, sft,
                                              fl, sl, yl, y2f, y2s,
                                              fmp, fmf, smp, smf,
                                              outf, outs, part);
    loss_reduce<<<1, 256, 0, stream>>>(part, outl);
}